// Round 10
// baseline (328.931 us; speedup 1.0000x reference)
//
#include <hip/hip_runtime.h>

#define GDIM 7
#define NN 49            // nodes per graph
#define FDIM 1024
#define HD 8
#define CD 128
#define ODIM 256
#define NC 14
#define MAXE 12          // max incoming edges: 8 spatial + 3 knn + self
#define KSPLIT 4         // knn split-k factor
#define GPSTRIDE 3192    // 56*57 floats per partial gram

typedef __attribute__((ext_vector_type(4))) float f32x4;
typedef __attribute__((ext_vector_type(8))) short s16x8;

struct us4 { unsigned short x, y, z, w; };

__device__ __forceinline__ unsigned short f2bf(float x) {
  unsigned u = __float_as_uint(x);
  return (unsigned short)((u + 0x7fffu + ((u >> 16) & 1u)) >> 16);  // RNE
}
__device__ __forceinline__ float bf2f(unsigned short h) {
  return __uint_as_float((unsigned)h << 16);
}

#define GLOAD_LDS16(g, l)                                          \
  __builtin_amdgcn_global_load_lds(                                \
      (const __attribute__((address_space(1))) void*)(g),          \
      (__attribute__((address_space(3))) void*)(l), 16, 0, 0)

// ---------------------------------------------------------------------------
// K1: relu + transpose  feat[B,1024,49] -> X fp32 + Xh/Xl bf16 split [B*49,1024]
// ---------------------------------------------------------------------------
__global__ void __launch_bounds__(256) relu_transpose_kernel(
    const float* __restrict__ F, float* __restrict__ X,
    unsigned short* __restrict__ Xh, unsigned short* __restrict__ Xl) {
  const int b  = blockIdx.x >> 4;          // 16 f-chunks of 64
  const int f0 = (blockIdx.x & 15) << 6;
  const int tid = threadIdx.x;
  __shared__ float lds[64 * NN];
  const float* src = F + (size_t)b * FDIM * NN + (size_t)f0 * NN;
  for (int idx = tid; idx < 64 * NN; idx += 256) lds[idx] = src[idx];
  __syncthreads();
  for (int pass = 0; pass < 13; pass++) {
    int n = pass * 4 + (tid >> 6);
    int fi = tid & 63;
    if (n < NN) {
      float v = lds[fi * NN + n];
      v = v > 0.f ? v : 0.f;
      size_t o = ((size_t)b * NN + n) * FDIM + f0 + fi;
      X[o] = v;
      unsigned short h = f2bf(v);
      Xh[o] = h;
      Xl[o] = f2bf(v - bf2f(h));
    }
  }
}

// ---------------------------------------------------------------------------
// K2a: kNN partial Gram — grid B*4, block p covers channels [p*256,(p+1)*256)
//      register-tiled fp32 (4x4 per thread, stride-14). 4 blocks/CU.
// ---------------------------------------------------------------------------
__global__ void __launch_bounds__(256) knn_partial(
    const float* __restrict__ X, float* __restrict__ gramP) {
  const int gid = blockIdx.x;
  const int b = gid >> 2, p = gid & 3;
  const int tid = threadIdx.x;
  __shared__ float xs[56][68];
  const float* Xb = X + (size_t)b * NN * FDIM + p * 256;

  const int tr = tid / 14, tc = tid % 14;   // active: tid < 196
  float acc[4][4];
#pragma unroll
  for (int i = 0; i < 4; i++)
#pragma unroll
    for (int j = 0; j < 4; j++) acc[i][j] = 0.f;

  for (int c0 = 0; c0 < 256; c0 += 64) {
    __syncthreads();
    for (int idx = tid; idx < NN * 16; idx += 256) {
      int n = idx >> 4, q = idx & 15;
      *(float4*)&xs[n][q << 2] =
          *(const float4*)&Xb[(size_t)n * FDIM + c0 + (q << 2)];
    }
    __syncthreads();
    if (tid < 196) {
#pragma unroll
      for (int k4 = 0; k4 < 64; k4 += 4) {
        float4 a[4], bb[4];
#pragma unroll
        for (int i = 0; i < 4; i++) a[i]  = *(const float4*)&xs[tr + 14 * i][k4];
#pragma unroll
        for (int j = 0; j < 4; j++) bb[j] = *(const float4*)&xs[tc + 14 * j][k4];
#pragma unroll
        for (int i = 0; i < 4; i++)
#pragma unroll
          for (int j = 0; j < 4; j++)
            acc[i][j] += a[i].x * bb[j].x + a[i].y * bb[j].y +
                         a[i].z * bb[j].z + a[i].w * bb[j].w;
      }
    }
  }
  if (tid < 196) {
    float* gp = gramP + (size_t)gid * GPSTRIDE;
#pragma unroll
    for (int i = 0; i < 4; i++)
#pragma unroll
      for (int j = 0; j < 4; j++)
        gp[(tr + 14 * i) * 57 + tc + 14 * j] = acc[i][j];
  }
}

// ---------------------------------------------------------------------------
// K2b: kNN combine + top-3 select (stable tie-break, matches jax top_k)
// ---------------------------------------------------------------------------
__global__ void __launch_bounds__(256) knn_select(
    const float* __restrict__ gramP, int* __restrict__ knn) {
  const int b = blockIdx.x, tid = threadIdx.x;
  __shared__ float gram[NN][50];
  const float* g0 = gramP + (size_t)(b * KSPLIT) * GPSTRIDE;
  for (int idx = tid; idx < NN * NN; idx += 256) {
    int r = idx / NN, c = idx % NN;
    float s = g0[r * 57 + c] + g0[GPSTRIDE + r * 57 + c] +
              g0[2 * GPSTRIDE + r * 57 + c] + g0[3 * GPSTRIDE + r * 57 + c];
    gram[r][c] = s;
  }
  __syncthreads();
  if (tid < NN) {
    const int n = tid;
    const float sqn = gram[n][n];
    float d0 = 1e30f, d1 = 1e30f, d2 = 1e30f;
    int i0 = 0, i1 = 0, i2 = 0;
    for (int m = 0; m < NN; m++) {
      if (m == n) continue;
      float d = sqn + gram[m][m] - 2.f * gram[n][m];
      if (d < d0)      { d2=d1; i2=i1; d1=d0; i1=i0; d0=d; i0=m; }
      else if (d < d1) { d2=d1; i2=i1; d1=d;  i1=m; }
      else if (d < d2) { d2=d;  i2=m; }
    }
    knn[((size_t)b * NN + n) * 3 + 0] = i0;
    knn[((size_t)b * NN + n) * 3 + 1] = i1;
    knn[((size_t)b * NN + n) * 3 + 2] = i2;
  }
}

// ---------------------------------------------------------------------------
// K-w: weight convert + transpose  W[K,N] fp32 -> WhT/WlT[N,K] bf16 split
// ---------------------------------------------------------------------------
__global__ void __launch_bounds__(256) wconvT_kernel(
    const float* __restrict__ W, int K, int N,
    unsigned short* __restrict__ WhT, unsigned short* __restrict__ WlT) {
  __shared__ float t[64][65];
  const int nbx = N >> 6;
  const int bx = blockIdx.x % nbx, by = blockIdx.x / nbx;
  const int r0 = by << 6, c0 = bx << 6;
  const int tid = threadIdx.x;
#pragma unroll
  for (int i = 0; i < 16; i++) {
    int r = i * 4 + (tid >> 6), c = tid & 63;
    t[r][c] = W[(size_t)(r0 + r) * N + c0 + c];
  }
  __syncthreads();
#pragma unroll
  for (int i = 0; i < 16; i++) {
    int n = i * 4 + (tid >> 6);   // row of WT (= col of W)
    int k = tid & 63;             // col of WT (= row of W)
    float x = t[k][n];
    unsigned short h = f2bf(x);
    size_t o = (size_t)(c0 + n) * K + r0 + k;
    WhT[o] = h;
    WlT[o] = f2bf(x - bf2f(h));
  }
}

// ---------------------------------------------------------------------------
// K3/K5: bf16x3-split MFMA GEMM, 128x128 tile, BK=64, 4 waves.
//   + bijective XCD swizzle + XOR chunk swizzle (verified r9: conflicts=0)
// ---------------------------------------------------------------------------
__global__ void __launch_bounds__(256) gemm_bf16x3(
    const unsigned short* __restrict__ A_h, const unsigned short* __restrict__ A_l,
    const unsigned short* __restrict__ BT_h, const unsigned short* __restrict__ BT_l,
    float* __restrict__ C, int M, int N, int K) {
  __shared__ unsigned short sAh[128][64], sAl[128][64];
  __shared__ unsigned short sBh[128][64], sBl[128][64];
  const int tid = threadIdx.x;
  const int w = tid >> 6, lane = tid & 63;
  const int nbx = N >> 7;
  const int nwg = gridDim.x;
  const int q = nwg >> 3, r = nwg & 7;
  const int xcd = blockIdx.x & 7, loc = blockIdx.x >> 3;
  const int wg = (xcd < r) ? (xcd * (q + 1) + loc)
                           : (r * (q + 1) + (xcd - r) * q + loc);
  const int bx = wg % nbx, by = wg / nbx;
  const int row0 = by << 7, col0 = bx << 7;
  const int wr = (w >> 1) << 6, wc = (w & 1) << 6;
  const int sgr = lane >> 3;
  const int schunk = lane & 7;
  const int fr = lane & 15;
  const int fq = lane >> 4;

  f32x4 acc[4][4];
#pragma unroll
  for (int m = 0; m < 4; m++)
#pragma unroll
    for (int n = 0; n < 4; n++) acc[m][n] = (f32x4){0.f, 0.f, 0.f, 0.f};

  for (int k0 = 0; k0 < K; k0 += 64) {
    __syncthreads();
#pragma unroll
    for (int i = 0; i < 4; i++) {
      const int rbase = (w << 5) + (i << 3);
      const int gr = rbase + sgr;
      const int sc = schunk ^ (gr & 7);
      const size_t ga = (size_t)(row0 + gr) * K + k0 + (sc << 3);
      GLOAD_LDS16(A_h + ga, &sAh[rbase][0]);
      GLOAD_LDS16(A_l + ga, &sAl[rbase][0]);
      const size_t gb = (size_t)(col0 + gr) * K + k0 + (sc << 3);
      GLOAD_LDS16(BT_h + gb, &sBh[rbase][0]);
      GLOAD_LDS16(BT_l + gb, &sBl[rbase][0]);
    }
    __syncthreads();
#pragma unroll
    for (int ks = 0; ks < 2; ks++) {
      const int cb = (ks << 2) + fq;
      s16x8 ah[4], al[4], bh[4], bl[4];
#pragma unroll
      for (int m = 0; m < 4; m++) {
        const int ra = wr + (m << 4) + fr;
        const int ca = (cb ^ (ra & 7)) << 3;
        ah[m] = *(const s16x8*)&sAh[ra][ca];
        al[m] = *(const s16x8*)&sAl[ra][ca];
        const int rb = wc + (m << 4) + fr;
        const int cbn = (cb ^ (rb & 7)) << 3;
        bh[m] = *(const s16x8*)&sBh[rb][cbn];
        bl[m] = *(const s16x8*)&sBl[rb][cbn];
      }
#pragma unroll
      for (int m = 0; m < 4; m++)
#pragma unroll
        for (int n = 0; n < 4; n++) {
          acc[m][n] = __builtin_amdgcn_mfma_f32_16x16x32_bf16(ah[m], bh[n], acc[m][n], 0, 0, 0);
          acc[m][n] = __builtin_amdgcn_mfma_f32_16x16x32_bf16(ah[m], bl[n], acc[m][n], 0, 0, 0);
          acc[m][n] = __builtin_amdgcn_mfma_f32_16x16x32_bf16(al[m], bh[n], acc[m][n], 0, 0, 0);
        }
    }
  }
  const int crow = fq << 2, ccol = fr;
#pragma unroll
  for (int m = 0; m < 4; m++)
#pragma unroll
    for (int n = 0; n < 4; n++)
#pragma unroll
      for (int v = 0; v < 4; v++)
        C[(size_t)(row0 + wr + (m << 4) + crow + v) * N + col0 + wc + (n << 4) + ccol] =
            acc[m][n][v];
}

// ---------------------------------------------------------------------------
// K4a: es/ed for layer 1 — one wave per node; lane = (head, 16-ch slice);
//      8-lane-group shfl reduce. es_g/ed_g [M][8].
// ---------------------------------------------------------------------------
__global__ void __launch_bounds__(256) esed1_kernel(
    const float* __restrict__ H, const float* __restrict__ a_src,
    const float* __restrict__ a_dst, float* __restrict__ es_g,
    float* __restrict__ ed_g) {
  const int n = blockIdx.x * 4 + (threadIdx.x >> 6);
  const int lane = threadIdx.x & 63;
  const int h = lane >> 3, sub = lane & 7;
  const float* hr = H + (size_t)n * FDIM + h * CD + sub * 16;
  const float* as = a_src + h * CD + sub * 16;
  const float* ad = a_dst + h * CD + sub * 16;
  float s1 = 0.f, s2 = 0.f;
#pragma unroll
  for (int c = 0; c < 16; c += 4) {
    float4 hv = *(const float4*)&hr[c];
    float4 av = *(const float4*)&as[c];
    float4 dv = *(const float4*)&ad[c];
    s1 += hv.x*av.x + hv.y*av.y + hv.z*av.z + hv.w*av.w;
    s2 += hv.x*dv.x + hv.y*dv.y + hv.z*dv.z + hv.w*dv.w;
  }
  s1 += __shfl_xor(s1, 1); s1 += __shfl_xor(s1, 2); s1 += __shfl_xor(s1, 4);
  s2 += __shfl_xor(s2, 1); s2 += __shfl_xor(s2, 2); s2 += __shfl_xor(s2, 4);
  if (sub == 0) {
    es_g[(size_t)n * HD + h] = s1;
    ed_g[(size_t)n * HD + h] = s2;
  }
}

// ---------------------------------------------------------------------------
// K4b: attn1 softmax — per graph: edge lists (written to global, shared with
//      layer 2) + per-(dst,head) softmax alphas from es/ed.
// ---------------------------------------------------------------------------
__global__ void __launch_bounds__(256) attn1_soft(
    const float* __restrict__ es_g, const float* __restrict__ ed_g,
    const int* __restrict__ knn, int* __restrict__ srcs_g,
    int* __restrict__ cnt_g, float* __restrict__ alpha_g) {
  const int b = blockIdx.x, tid = threadIdx.x;
  __shared__ float es[NN][HD], ed[NN][HD];
  __shared__ int srcs[NN][MAXE];
  __shared__ int cnt[NN];
  for (int p = tid; p < NN * HD; p += 256) {
    es[p >> 3][p & 7] = es_g[(size_t)b * NN * HD + p];
    ed[p >> 3][p & 7] = ed_g[(size_t)b * NN * HD + p];
  }
  if (tid < NN) {
    int i = tid, r = i / GDIM, c = i % GDIM, k = 0;
    for (int dr = -1; dr <= 1; dr++)
      for (int dc = -1; dc <= 1; dc++) {
        if (dr == 0 && dc == 0) continue;
        int rr = r + dr, cc = c + dc;
        if (rr >= 0 && rr < GDIM && cc >= 0 && cc < GDIM)
          srcs[i][k++] = rr * GDIM + cc;
      }
    srcs[i][k++] = knn[((size_t)b * NN + i) * 3 + 0];
    srcs[i][k++] = knn[((size_t)b * NN + i) * 3 + 1];
    srcs[i][k++] = knn[((size_t)b * NN + i) * 3 + 2];
    srcs[i][k++] = i;   // self loop
    cnt[i] = k;
    cnt_g[(size_t)b * NN + i] = k;
    for (int j = 0; j < MAXE; j++)
      srcs_g[((size_t)b * NN + i) * MAXE + j] = srcs[i][j < k ? j : 0];
  }
  __syncthreads();
  for (int p = tid; p < NN * HD; p += 256) {
    int i = p >> 3, h = p & 7;
    int k = cnt[i];
    float e[MAXE];
    float m = -1e30f;
#pragma unroll
    for (int j = 0; j < MAXE; j++) {
      if (j < k) {
        float v = es[srcs[i][j]][h] + ed[i][h];
        v = v >= 0.f ? v : 0.2f * v;   // leaky_relu 0.2
        e[j] = v;
        m = fmaxf(m, v);
      }
    }
    float denom = 0.f;
#pragma unroll
    for (int j = 0; j < MAXE; j++) {
      if (j < k) { e[j] = expf(e[j] - m); denom += e[j]; }
    }
    float inv = 1.f / fmaxf(denom, 1e-16f);
#pragma unroll
    for (int j = 0; j < MAXE; j++) {
      if (j < k)
        alpha_g[(((size_t)b * NN + i) * MAXE + j) * HD + h] = e[j] * inv;
    }
  }
}

// ---------------------------------------------------------------------------
// K4c: attn1 aggregation — block per (graph,node); emits Z1 as bf16 hi/lo
// ---------------------------------------------------------------------------
__global__ void __launch_bounds__(256) attn1_agg(
    const float* __restrict__ H, const int* __restrict__ srcs_g,
    const int* __restrict__ cnt_g, const float* __restrict__ alpha_g,
    const float* __restrict__ b1,
    unsigned short* __restrict__ Zh, unsigned short* __restrict__ Zl) {
  const int bid = blockIdx.x;          // = b*NN + i
  const int b = bid / NN;
  const int tid = threadIdx.x;
  __shared__ float al[MAXE][HD];
  __shared__ int ss[MAXE];
  const int k = cnt_g[bid];
  if (tid < MAXE * HD) al[tid >> 3][tid & 7] = alpha_g[(size_t)bid * MAXE * HD + tid];
  if (tid < MAXE) ss[tid] = srcs_g[(size_t)bid * MAXE + tid];
  __syncthreads();
  const float4* Hb = (const float4*)(H + (size_t)b * NN * FDIM);
  const int h = tid >> 5;
  float4 acc = ((const float4*)b1)[tid];
  for (int j = 0; j < k; j++) {
    float a = al[j][h];
    float4 v = Hb[(size_t)ss[j] * (FDIM / 4) + tid];
    acc.x += a * v.x; acc.y += a * v.y; acc.z += a * v.z; acc.w += a * v.w;
  }
  acc.x = acc.x > 0.f ? acc.x : expm1f(acc.x);
  acc.y = acc.y > 0.f ? acc.y : expm1f(acc.y);
  acc.z = acc.z > 0.f ? acc.z : expm1f(acc.z);
  acc.w = acc.w > 0.f ? acc.w : expm1f(acc.w);
  us4 hv, lv;
  hv.x = f2bf(acc.x); lv.x = f2bf(acc.x - bf2f(hv.x));
  hv.y = f2bf(acc.y); lv.y = f2bf(acc.y - bf2f(hv.y));
  hv.z = f2bf(acc.z); lv.z = f2bf(acc.z - bf2f(hv.z));
  hv.w = f2bf(acc.w); lv.w = f2bf(acc.w - bf2f(hv.w));
  *(us4*)&Zh[(size_t)bid * FDIM + (tid << 2)] = hv;
  *(us4*)&Zl[(size_t)bid * FDIM + (tid << 2)] = lv;
}

// ---------------------------------------------------------------------------
// K6a: es/ed for layer 2 (H=1, C=256) — one wave per node, full-wave reduce
// ---------------------------------------------------------------------------
__global__ void __launch_bounds__(256) esed2_kernel(
    const float* __restrict__ H2, const float* __restrict__ a_src,
    const float* __restrict__ a_dst, float* __restrict__ es_g,
    float* __restrict__ ed_g) {
  const int n = blockIdx.x * 4 + (threadIdx.x >> 6);
  const int lane = threadIdx.x & 63;
  float4 hv = *(const float4*)&H2[(size_t)n * ODIM + lane * 4];
  float4 av = *(const float4*)&a_src[lane * 4];
  float4 dv = *(const float4*)&a_dst[lane * 4];
  float s1 = hv.x*av.x + hv.y*av.y + hv.z*av.z + hv.w*av.w;
  float s2 = hv.x*dv.x + hv.y*dv.y + hv.z*dv.z + hv.w*dv.w;
#pragma unroll
  for (int m = 1; m < 64; m <<= 1) {
    s1 += __shfl_xor(s1, m);
    s2 += __shfl_xor(s2, m);
  }
  if (lane == 0) { es_g[n] = s1; ed_g[n] = s2; }
}

// ---------------------------------------------------------------------------
// K6b: attn2 softmax — per graph, reuses srcs_g/cnt_g from layer 1
// ---------------------------------------------------------------------------
__global__ void __launch_bounds__(256) attn2_soft(
    const float* __restrict__ es_g, const float* __restrict__ ed_g,
    const int* __restrict__ srcs_g, const int* __restrict__ cnt_g,
    float* __restrict__ alpha_g) {
  const int b = blockIdx.x, tid = threadIdx.x;
  __shared__ float es[NN], ed[NN];
  if (tid < NN) {
    es[tid] = es_g[(size_t)b * NN + tid];
    ed[tid] = ed_g[(size_t)b * NN + tid];
  }
  __syncthreads();
  if (tid < NN) {
    const int i = tid;
    const int k = cnt_g[(size_t)b * NN + i];
    float e[MAXE];
    float m = -1e30f;
#pragma unroll
    for (int j = 0; j < MAXE; j++) {
      if (j < k) {
        int s = srcs_g[((size_t)b * NN + i) * MAXE + j];
        float v = es[s] + ed[i];
        v = v >= 0.f ? v : 0.2f * v;
        e[j] = v;
        m = fmaxf(m, v);
      }
    }
    float denom = 0.f;
#pragma unroll
    for (int j = 0; j < MAXE; j++) {
      if (j < k) { e[j] = expf(e[j] - m); denom += e[j]; }
    }
    float inv = 1.f / fmaxf(denom, 1e-16f);
#pragma unroll
    for (int j = 0; j < MAXE; j++) {
      if (j < k) alpha_g[((size_t)b * NN + i) * MAXE + j] = e[j] * inv;
    }
  }
}

// ---------------------------------------------------------------------------
// K6c: attn2 aggregation — block per (graph,node); thread = channel
// ---------------------------------------------------------------------------
__global__ void __launch_bounds__(256) attn2_agg(
    const float* __restrict__ H2, const int* __restrict__ srcs_g,
    const int* __restrict__ cnt_g, const float* __restrict__ alpha_g,
    const float* __restrict__ b2, float* __restrict__ Z2) {
  const int bid = blockIdx.x;
  const int b = bid / NN;
  const int tid = threadIdx.x;
  __shared__ float al[MAXE];
  __shared__ int ss[MAXE];
  const int k = cnt_g[bid];
  if (tid < MAXE) {
    al[tid] = alpha_g[(size_t)bid * MAXE + tid];
    ss[tid] = srcs_g[(size_t)bid * MAXE + tid];
  }
  __syncthreads();
  const float* Hb = H2 + (size_t)b * NN * ODIM;
  float acc = b2[tid];
  for (int j = 0; j < k; j++)
    acc += al[j] * Hb[(size_t)ss[j] * ODIM + tid];
  acc = acc > 0.f ? acc : expm1f(acc);
  Z2[(size_t)bid * ODIM + tid] = acc;
}

// ---------------------------------------------------------------------------
// K7: classifier with fused mean pool
// ---------------------------------------------------------------------------
__global__ void __launch_bounds__(256) classifier_kernel(
    const float* __restrict__ Z2, const float* __restrict__ Wc1,
    const float* __restrict__ bc1, const float* __restrict__ Wc2,
    const float* __restrict__ bc2, float* __restrict__ out) {
  const int b = blockIdx.x, tid = threadIdx.x;
  __shared__ float p[ODIM];
  __shared__ float t[ODIM];
  float s = 0.f;
  for (int i = 0; i < NN; i++)
    s += Z2[((size_t)b * NN + i) * ODIM + tid];
  p[tid] = s * (1.f / 49.f);
  __syncthreads();
  float a = bc1[tid];
  for (int c = 0; c < ODIM; c++) a += p[c] * Wc1[(size_t)c * ODIM + tid];
  t[tid] = a > 0.f ? a : 0.f;
  __syncthreads();
  if (tid < NC) {
    float o = bc2[tid];
    for (int j = 0; j < ODIM; j++) o += t[j] * Wc2[(size_t)j * NC + tid];
    out[(size_t)b * NC + tid] = o;
  }
}

// ---------------------------------------------------------------------------
extern "C" void kernel_launch(void* const* d_in, const int* in_sizes, int n_in,
                              void* d_out, int out_size, void* d_ws, size_t ws_size,
                              hipStream_t stream) {
  const float* feat   = (const float*)d_in[0];
  const float* W1     = (const float*)d_in[1];
  const float* a_src1 = (const float*)d_in[2];
  const float* a_dst1 = (const float*)d_in[3];
  const float* b1     = (const float*)d_in[4];
  const float* W2     = (const float*)d_in[5];
  const float* a_src2 = (const float*)d_in[6];
  const float* a_dst2 = (const float*)d_in[7];
  const float* b2     = (const float*)d_in[8];
  const float* Wc1    = (const float*)d_in[9];
  const float* bc1    = (const float*)d_in[10];
  const float* Wc2    = (const float*)d_in[11];
  const float* bc2    = (const float*)d_in[12];

  const int B = in_sizes[0] / (FDIM * NN);   // 256
  const int M = B * NN;                       // 12544

  const size_t xE = (size_t)M * FDIM;         // 12,845,056
  float* X  = (float*)d_ws;                   // fp32 X; later H2 (M*ODIM)
  float* H1 = X + xE;                         // fp32 H1; later Z2 (M*ODIM)
  unsigned short* Xh = (unsigned short*)(H1 + xE);  // bf16 hi; later Z1h
  unsigned short* Xl = Xh + xE;                     // bf16 lo; later Z1l
  unsigned short* W1hT = Xl + xE;                   // [1024][1024]
  unsigned short* W1lT = W1hT + (size_t)FDIM * FDIM;
  unsigned short* W2hT = W1lT + (size_t)FDIM * FDIM;  // [256][1024]
  unsigned short* W2lT = W2hT + (size_t)ODIM * FDIM;
  int*   knn    = (int*)(W2lT + (size_t)ODIM * FDIM);
  int*   srcs_g = knn + (size_t)M * 3;
  int*   cnt_g  = srcs_g + (size_t)M * MAXE;
  float* alpha1 = (float*)(cnt_g + M);
  float* alpha2 = alpha1 + (size_t)M * MAXE * HD;
  float* gramP  = alpha2 + (size_t)M * MAXE;          // B*4*3192
  float* es1    = gramP + (size_t)B * KSPLIT * GPSTRIDE;  // [M][8]
  float* ed1    = es1 + (size_t)M * HD;
  float* es2    = ed1 + (size_t)M * HD;               // [M]
  float* ed2    = es2 + M;
  // aliases (producer strictly after last reader of the original)
  float* H2  = X;      // X dead after knn_partial
  float* Z2  = H1;     // H1 dead after attn1_agg
  unsigned short* Z1h = Xh;  // Xh/Xl dead after gemm1
  unsigned short* Z1l = Xl;

  relu_transpose_kernel<<<B * 16, 256, 0, stream>>>(feat, X, Xh, Xl);
  knn_partial<<<B * KSPLIT, 256, 0, stream>>>(X, gramP);
  knn_select<<<B, 256, 0, stream>>>(gramP, knn);
  wconvT_kernel<<<(FDIM / 64) * (FDIM / 64), 256, 0, stream>>>(W1, FDIM, FDIM, W1hT, W1lT);
  wconvT_kernel<<<(FDIM / 64) * (ODIM / 64), 256, 0, stream>>>(W2, FDIM, ODIM, W2hT, W2lT);
  // H1 = X @ W1
  gemm_bf16x3<<<(M / 128) * (FDIM / 128), 256, 0, stream>>>(
      Xh, Xl, W1hT, W1lT, H1, M, FDIM, FDIM);
  // attention layer 1 -> Z1 (bf16 hi/lo into Xh/Xl)
  esed1_kernel<<<M / 4, 256, 0, stream>>>(H1, a_src1, a_dst1, es1, ed1);
  attn1_soft<<<B, 256, 0, stream>>>(es1, ed1, knn, srcs_g, cnt_g, alpha1);
  attn1_agg<<<M, 256, 0, stream>>>(H1, srcs_g, cnt_g, alpha1, b1, Z1h, Z1l);
  // H2 = Z1 @ W2  (into X buffer)
  gemm_bf16x3<<<(M / 128) * (ODIM / 128), 256, 0, stream>>>(
      Z1h, Z1l, W2hT, W2lT, H2, M, ODIM, FDIM);
  // attention layer 2 -> Z2 (into H1 buffer)
  esed2_kernel<<<M / 4, 256, 0, stream>>>(H2, a_src2, a_dst2, es2, ed2);
  attn2_soft<<<B, 256, 0, stream>>>(es2, ed2, srcs_g, cnt_g, alpha2);
  attn2_agg<<<M, 256, 0, stream>>>(H2, srcs_g, cnt_g, alpha2, b2, Z2);
  classifier_kernel<<<B, 256, 0, stream>>>(Z2, Wc1, bc1, Wc2, bc2, (float*)d_out);
}